// Round 1
// baseline (180.807 us; speedup 1.0000x reference)
//
#include <hip/hip_runtime.h>

// DCN-v2 low-rank mixture, L=3 E=4 D=512 R=64 B=16384.
// gate = softmax over size-1 axis == 1  -> G unused.
// xl' = x0 * (sum_e U_e tanh(C_e tanh(V_e^T xl)) + 4*bias) + xl, rows independent.
// Fully fused single kernel, bf16 MFMA (16x16x32), fp32 xl state in VGPRs.

#define NL 3
#define NE 4
#define DD 512
#define RR 64
#define ROWS 32   // rows per block; grid = 16384/32 = 512 blocks

typedef __attribute__((ext_vector_type(8))) short bf16x8;   // 8 bf16 = 4 VGPR
typedef __attribute__((ext_vector_type(4))) float f32x4;

#define MFMA(a, b, c) __builtin_amdgcn_mfma_f32_16x16x32_bf16((a), (b), (c), 0, 0, 0)

__device__ __forceinline__ short bf16rn(float f) {   // round-to-nearest-even f32->bf16
    unsigned u = __builtin_bit_cast(unsigned, f);
    u += 0x7fffu + ((u >> 16) & 1u);
    return (short)(u >> 16);
}

__device__ __forceinline__ float ftanh(float x) {
    // tanh(x) = 1 - 2/(exp2(2x*log2e)+1); exact at +-inf, ~1e-6 abs error
    float t = __builtin_amdgcn_exp2f(x * 2.8853900817779268f);
    return 1.0f - 2.0f * __builtin_amdgcn_rcpf(t + 1.0f);
}

// ---- prep: cast weights to bf16, transpose V and C for contiguous-k B-fragments ----
// Vb[(l,e)][r][d] = V[(l,e)][d][r];  Ub = U (layout already [e][d][s], k=s contiguous);
// Ct[(l,e)][s][r] = C[(l,e)][r][s]
__global__ void prep_kernel(const float* __restrict__ U, const float* __restrict__ V,
                            const float* __restrict__ C,
                            short* __restrict__ Vb, short* __restrict__ Ub,
                            short* __restrict__ Ct)
{
    int tid  = blockIdx.x * 256 + threadIdx.x;
    int nthr = gridDim.x * 256;
    for (int i = tid; i < NL * NE * DD * RR; i += nthr) Ub[i] = bf16rn(U[i]);
    for (int i = tid; i < NL * NE * DD * RR; i += nthr) {
        int le = i >> 15;            // / (512*64)
        int rem = i & 32767;
        int r = rem >> 9;            // / 512
        int d = rem & 511;
        Vb[i] = bf16rn(V[(le << 15) + (d << 6) + r]);
    }
    for (int i = tid; i < NL * NE * RR * RR; i += nthr) {
        int le = i >> 12;
        int rem = i & 4095;
        int s = rem >> 6;
        int r = rem & 63;
        Ct[i] = bf16rn(C[(le << 12) + (r << 6) + s]);
    }
}

// XOR swizzle: breaks the 16-way bank conflict of row-major bf16 tiles on ds_read_b128
#define XLB_ADDR(row, colbyte) (((row) * (DD * 2)) + ((colbyte) ^ (((row) & 7) << 4)))
#define VB_ADDR(row, colbyte)  (((row) * (NE * RR * 2)) + ((colbyte) ^ (((row) & 7) << 4)))

__global__ __launch_bounds__(256, 2) void dcn_main(
    const float* __restrict__ x,
    const float* __restrict__ bias,
    const short* __restrict__ Vb,
    const short* __restrict__ Ub,
    const short* __restrict__ Ct,
    float* __restrict__ out)
{
    __shared__ char xl_b[ROWS * DD * 2];        // 32 KiB bf16 xl tile (swizzled)
    __shared__ char vbuf[ROWS * NE * RR * 2];   // 16 KiB bf16 v/cv tile (swizzled, reused)

    const int t   = threadIdx.x;
    const int w   = t >> 6;          // wave 0..3
    const int ln  = t & 63;
    const int l15 = ln & 15;
    const int kg  = ln >> 4;         // k-group 0..3
    const int row_base = blockIdx.x * ROWS;

    // ---- preamble: stage bf16(x) tile into xl_b; x0 (bf16-packed) + xl (fp32) into regs ----
    #pragma unroll
    for (int q = 0; q < 16; ++q) {
        int p   = t + q * 256;
        int row = p >> 7;                 // 128 float4 per row
        int d4  = (p & 127) << 2;
        const float4 v4 = *(const float4*)(x + (size_t)(row_base + row) * DD + d4);
        uint2 pk;
        pk.x = (unsigned)(unsigned short)bf16rn(v4.x) | ((unsigned)(unsigned short)bf16rn(v4.y) << 16);
        pk.y = (unsigned)(unsigned short)bf16rn(v4.z) | ((unsigned)(unsigned short)bf16rn(v4.w) << 16);
        *(uint2*)(xl_b + XLB_ADDR(row, d4 * 2)) = pk;
    }

    float    xlr[2][8][4];   // fp32 xl state, GEMM3 D-frag layout
    unsigned x0p[2][8][2];   // x0 packed as bf16x2 (only scales the small correction term)
    #pragma unroll
    for (int mt = 0; mt < 2; ++mt)
      #pragma unroll
      for (int nt = 0; nt < 8; ++nt) {
          int col = w * 128 + nt * 16 + l15;
          const float* xp = x + (size_t)(row_base + mt * 16 + kg * 4) * DD + col;
          float v0 = xp[0], v1 = xp[DD], v2 = xp[2 * DD], v3 = xp[3 * DD];
          xlr[mt][nt][0] = v0; xlr[mt][nt][1] = v1; xlr[mt][nt][2] = v2; xlr[mt][nt][3] = v3;
          x0p[mt][nt][0] = (unsigned)(unsigned short)bf16rn(v0) | ((unsigned)(unsigned short)bf16rn(v1) << 16);
          x0p[mt][nt][1] = (unsigned)(unsigned short)bf16rn(v2) | ((unsigned)(unsigned short)bf16rn(v3) << 16);
      }
    __syncthreads();

    for (int layer = 0; layer < NL; ++layer) {
        const short* Vl = Vb + layer * (NE * DD * RR);
        const short* Ul = Ub + layer * (NE * DD * RR);
        const short* Cl = Ct + layer * (NE * RR * RR);
        const float* bl = bias + layer * DD;

        // ---- GEMM1: v = tanh(xl @ V), this wave owns cols [w*64, w*64+64) ----
        f32x4 acc1[2][4];
        #pragma unroll
        for (int mt = 0; mt < 2; ++mt)
          #pragma unroll
          for (int nt = 0; nt < 4; ++nt) { f32x4 z = {0.f, 0.f, 0.f, 0.f}; acc1[mt][nt] = z; }

        #pragma unroll 4
        for (int ks = 0; ks < 16; ++ks) {
            const int d0 = ks * 32 + kg * 8;
            bf16x8 a0 = *(const bf16x8*)(xl_b + XLB_ADDR(l15,      d0 * 2));
            bf16x8 a1 = *(const bf16x8*)(xl_b + XLB_ADDR(l15 + 16, d0 * 2));
            #pragma unroll
            for (int nt = 0; nt < 4; ++nt) {
                bf16x8 b = *(const bf16x8*)(Vl + (size_t)(w * 64 + nt * 16 + l15) * DD + d0);
                acc1[0][nt] = MFMA(a0, b, acc1[0][nt]);
                acc1[1][nt] = MFMA(a1, b, acc1[1][nt]);
            }
        }
        #pragma unroll
        for (int mt = 0; mt < 2; ++mt)
          #pragma unroll
          for (int nt = 0; nt < 4; ++nt)
            #pragma unroll
            for (int r = 0; r < 4; ++r) {
                int row = mt * 16 + kg * 4 + r;
                int col = w * 64 + nt * 16 + l15;
                *(short*)(vbuf + VB_ADDR(row, col * 2)) = bf16rn(ftanh(acc1[mt][nt][r]));
            }
        __syncthreads();

        // ---- GEMM2: cv = tanh(v @ C_e), expert e == wave id (block-diagonal) ----
        f32x4 acc2[2][4];
        #pragma unroll
        for (int mt = 0; mt < 2; ++mt)
          #pragma unroll
          for (int nt = 0; nt < 4; ++nt) { f32x4 z = {0.f, 0.f, 0.f, 0.f}; acc2[mt][nt] = z; }

        #pragma unroll
        for (int kc = 0; kc < 2; ++kc) {
            const int r0 = kc * 32 + kg * 8;
            bf16x8 a0 = *(const bf16x8*)(vbuf + VB_ADDR(l15,      (w * 64 + r0) * 2));
            bf16x8 a1 = *(const bf16x8*)(vbuf + VB_ADDR(l15 + 16, (w * 64 + r0) * 2));
            #pragma unroll
            for (int nt = 0; nt < 4; ++nt) {
                bf16x8 b = *(const bf16x8*)(Cl + (size_t)w * (RR * RR) + (nt * 16 + l15) * RR + r0);
                acc2[0][nt] = MFMA(a0, b, acc2[0][nt]);
                acc2[1][nt] = MFMA(a1, b, acc2[1][nt]);
            }
        }
        float cvv[2][4][4];
        #pragma unroll
        for (int mt = 0; mt < 2; ++mt)
          #pragma unroll
          for (int nt = 0; nt < 4; ++nt)
            #pragma unroll
            for (int r = 0; r < 4; ++r) cvv[mt][nt][r] = ftanh(acc2[mt][nt][r]);
        __syncthreads();   // all GEMM2 reads of vbuf done
        #pragma unroll
        for (int mt = 0; mt < 2; ++mt)
          #pragma unroll
          for (int nt = 0; nt < 4; ++nt)
            #pragma unroll
            for (int r = 0; r < 4; ++r) {
                int row = mt * 16 + kg * 4 + r;
                int col = w * 64 + nt * 16 + l15;
                *(short*)(vbuf + VB_ADDR(row, col * 2)) = bf16rn(cvv[mt][nt][r]);
            }
        __syncthreads();

        // ---- GEMM3: ucv_sum = cv @ W, W[(e,s)][d] = U[e][d][s]; wave owns cols [w*128, w*128+128) ----
        f32x4 acc3[2][8];
        #pragma unroll
        for (int mt = 0; mt < 2; ++mt)
          #pragma unroll
          for (int nt = 0; nt < 8; ++nt) { f32x4 z = {0.f, 0.f, 0.f, 0.f}; acc3[mt][nt] = z; }

        #pragma unroll 2
        for (int ks = 0; ks < 8; ++ks) {
            const int k0 = ks * 32 + kg * 8;
            bf16x8 a0 = *(const bf16x8*)(vbuf + VB_ADDR(l15,      k0 * 2));
            bf16x8 a1 = *(const bf16x8*)(vbuf + VB_ADDR(l15 + 16, k0 * 2));
            const int e  = ks >> 1;        // K=32 block stays inside one expert
            const int s0 = k0 & 63;
            #pragma unroll
            for (int nt = 0; nt < 8; ++nt) {
                int dcol = w * 128 + nt * 16 + l15;
                bf16x8 b = *(const bf16x8*)(Ul + (size_t)e * (DD * RR) + dcol * RR + s0);
                acc3[0][nt] = MFMA(a0, b, acc3[0][nt]);
                acc3[1][nt] = MFMA(a1, b, acc3[1][nt]);
            }
        }

        // ---- epilogue: xl' = x0*(ucv + 4*bias) + xl  (fp32 state in regs) ----
        const bool lastL = (layer == NL - 1);
        #pragma unroll
        for (int nt = 0; nt < 8; ++nt) {
            int col = w * 128 + nt * 16 + l15;
            float bv = 4.0f * bl[col];
            #pragma unroll
            for (int mt = 0; mt < 2; ++mt) {
                unsigned p0 = x0p[mt][nt][0], p1 = x0p[mt][nt][1];
                float x0v0 = __builtin_bit_cast(float, p0 << 16);
                float x0v1 = __builtin_bit_cast(float, p0 & 0xffff0000u);
                float x0v2 = __builtin_bit_cast(float, p1 << 16);
                float x0v3 = __builtin_bit_cast(float, p1 & 0xffff0000u);
                xlr[mt][nt][0] = x0v0 * (acc3[mt][nt][0] + bv) + xlr[mt][nt][0];
                xlr[mt][nt][1] = x0v1 * (acc3[mt][nt][1] + bv) + xlr[mt][nt][1];
                xlr[mt][nt][2] = x0v2 * (acc3[mt][nt][2] + bv) + xlr[mt][nt][2];
                xlr[mt][nt][3] = x0v3 * (acc3[mt][nt][3] + bv) + xlr[mt][nt][3];
            }
        }
        if (lastL) {
            #pragma unroll
            for (int mt = 0; mt < 2; ++mt)
              #pragma unroll
              for (int nt = 0; nt < 8; ++nt) {
                  int col = w * 128 + nt * 16 + l15;
                  float* op = out + (size_t)(row_base + mt * 16 + kg * 4) * DD + col;
                  op[0]      = xlr[mt][nt][0];
                  op[DD]     = xlr[mt][nt][1];
                  op[2 * DD] = xlr[mt][nt][2];
                  op[3 * DD] = xlr[mt][nt][3];
              }
        } else {
            // refresh bf16 xl tile for next layer's GEMM1 A-fragments
            #pragma unroll
            for (int mt = 0; mt < 2; ++mt)
              #pragma unroll
              for (int nt = 0; nt < 8; ++nt) {
                  int col = w * 128 + nt * 16 + l15;
                  #pragma unroll
                  for (int r = 0; r < 4; ++r) {
                      int row = mt * 16 + kg * 4 + r;
                      *(short*)(xl_b + XLB_ADDR(row, col * 2)) = bf16rn(xlr[mt][nt][r]);
                  }
              }
            __syncthreads();
        }
    }
}

extern "C" void kernel_launch(void* const* d_in, const int* in_sizes, int n_in,
                              void* d_out, int out_size, void* d_ws, size_t ws_size,
                              hipStream_t stream) {
    const float* x    = (const float*)d_in[0];
    const float* U    = (const float*)d_in[1];
    const float* V    = (const float*)d_in[2];
    const float* C    = (const float*)d_in[3];
    // d_in[4] = G : unused (gate == 1 exactly)
    const float* bias = (const float*)d_in[5];
    float* out = (float*)d_out;

    short* Vb = (short*)d_ws;                 // 786432 B
    short* Ub = Vb + NL * NE * DD * RR;       // 786432 B
    short* Ct = Ub + NL * NE * DD * RR;       // 98304 B  (total ~1.6 MiB)

    prep_kernel<<<dim3(256), dim3(256), 0, stream>>>(U, V, C, Vb, Ub, Ct);
    dcn_main<<<dim3(16384 / ROWS), dim3(256), 0, stream>>>(x, bias, Vb, Ub, Ct, out);
}